// Round 19
// baseline (221.426 us; speedup 1.0000x reference)
//
#include <hip/hip_runtime.h>
#include <stdint.h>

#define BATCH 64
#define NN 131072
#define NCOARSE 256
#define SLOT 704
#define CHUNK 8192
#define NSUB 1024
#define EMASK17 0x1FFFFu
#define POSCAP 1536
#define NEGCAP 1536
#define SPOSCAP 96
#define SNEGCAP 160

typedef uint32_t u32;
typedef uint64_t u64;

__device__ __forceinline__ u32 rotl32(u32 v, int d) { return (v << d) | (v >> (32 - d)); }

// Exact port of JAX threefry2x32 block cipher
__device__ __forceinline__ void threefry2x32(u32 k0, u32 k1, u32 x0, u32 x1, u32& o0, u32& o1) {
  u32 ks2 = k0 ^ k1 ^ 0x1BD11BDAu;
  x0 += k0; x1 += k1;
#define TF_R(r) { x0 += x1; x1 = rotl32(x1, r); x1 ^= x0; }
  TF_R(13) TF_R(15) TF_R(26) TF_R(6)
  x0 += k1;  x1 += ks2 + 1u;
  TF_R(17) TF_R(29) TF_R(16) TF_R(24)
  x0 += ks2; x1 += k0 + 2u;
  TF_R(13) TF_R(15) TF_R(26) TF_R(6)
  x0 += k0;  x1 += k1 + 3u;
  TF_R(17) TF_R(29) TF_R(16) TF_R(24)
  x0 += k1;  x1 += ks2 + 4u;
  TF_R(13) TF_R(15) TF_R(26) TF_R(6)
  x0 += ks2; x1 += k0 + 5u;
#undef TF_R
  o0 = x0; o1 = x1;
}

// threefry_partitionable: bits[i] = o0 ^ o1 of cipher(key, (0, i))
__device__ __forceinline__ u32 tf_bits(u32 k0, u32 k1, u32 i) {
  u32 o0, o1;
  threefry2x32(k0, k1, 0u, i, o0, o1);
  return o0 ^ o1;
}

// kb = cipher((0,42),(0,b)); round1 sub = cipher(kb,(0,1));
// round2 sub = cipher(cipher(kb,(0,0)),(0,1))
__device__ void batch_round_key(int b, int round, u32& rk0, u32& rk1) {
  u32 kb0, kb1;
  threefry2x32(0u, 42u, 0u, (u32)b, kb0, kb1);
  if (round == 1) { threefry2x32(kb0, kb1, 0u, 1u, rk0, rk1); return; }
  u32 c0, c1;
  threefry2x32(kb0, kb1, 0u, 0u, c0, c1);
  threefry2x32(c0, c1, 0u, 1u, rk0, rk1);
}

// meta[g*16+ .]: 0 = pos survivor count, 1 = neg survivor count, 2 = np, 3 = nn.
// 64B stride per batch (R8 lesson: returning atomics to one line serialize).

// Coarse bucket scatter, 512 threads x 16 elems (CHUNK 8192 — R16 showed run
// lengthening speeds the scatter). Stages the u32 token (bin|label|e, 32KB
// LDS) and recomputes k1 in the terminal write loop to emit the FULL u64 key
// (R17 lesson: passB must receive full keys; the recompute here is off any
// barrier-interleaved critical path — 16 independent iters pipeline against
// scatterA's ~60% idle VALU).
__global__ __launch_bounds__(512) void scatterA_kernel(u32* __restrict__ cursor, u32* __restrict__ meta,
                                                       u64* __restrict__ binned,
                                                       const int* __restrict__ posg, const int* __restrict__ negg,
                                                       const int* __restrict__ igng, int batch0) {
  __shared__ u32 sk[2];
  __shared__ u32 hist[NCOARSE];
  __shared__ u32 lstart[NCOARSE];
  __shared__ u32 gbase[NCOARSE];
  __shared__ u32 staged[CHUNK];
  __shared__ u32 wtot4[4];
  __shared__ u32 cntPN[2];
  int g = blockIdx.y;
  int b = batch0 + g;
  int tid = threadIdx.x;
  if (tid == 0) { u32 k0, k1; batch_round_key(b, 1, k0, k1); sk[0] = k0; sk[1] = k1; }
  if (tid < 2) cntPN[tid] = 0;
  if (tid < NCOARSE) hist[tid] = 0;
  __syncthreads();
  u32 base = blockIdx.x * CHUNK;
  u32 recs[16]; u32 rr[16];
  u32 myp = 0, myn = 0;
  const int4* P4 = (const int4*)(posg + (size_t)b * NN);
  const int4* Q4 = (const int4*)(negg + (size_t)b * NN);
  const int4* I4 = (const int4*)(igng + (size_t)b * NN);
#pragma unroll
  for (int j = 0; j < 4; j++) {
    u32 e0 = base + j * 2048 + tid * 4;
    int4 pv = P4[e0 >> 2];
    int4 nv = Q4[e0 >> 2];
    int4 iv = I4[e0 >> 2];
#pragma unroll
    for (int m = 0; m < 4; m++) {
      u32 e = e0 + m;
      int p = (&pv.x)[m] != 0, n = (&nv.x)[m] != 0, ig = (&iv.x)[m] != 0;
      u32 label = ((p | n) && !ig) ? (p ? 1u : 2u) : 0u;
      myp += (label == 1);
      myn += (label == 2);
      u32 k1 = tf_bits(sk[0], sk[1], e);
      u32 bin = k1 >> 24;
      rr[j * 4 + m] = atomicAdd(&hist[bin], 1u);
      recs[j * 4 + m] = (bin << 24) | (label << 17) | e;
    }
  }
#pragma unroll
  for (int off = 32; off > 0; off >>= 1) {
    myp += __shfl_down(myp, off, 64);
    myn += __shfl_down(myn, off, 64);
  }
  if ((tid & 63) == 0) { atomicAdd(&cntPN[0], myp); atomicAdd(&cntPN[1], myn); }
  __syncthreads();
  // shfl-based exclusive scan of hist (256 entries, first 256 threads)
  u32 hv = 0, hs = 0;
  if (tid < NCOARSE) {
    hv = hist[tid];
    hs = hv;
#pragma unroll
    for (int off = 1; off < 64; off <<= 1) {
      u32 t = __shfl_up(hs, off, 64);
      if ((tid & 63) >= off) hs += t;
    }
    if ((tid & 63) == 63) wtot4[tid >> 6] = hs;
  }
  __syncthreads();
  if (tid < NCOARSE) {
    u32 woff = 0;
    for (int w = 0; w < (tid >> 6); w++) woff += wtot4[w];
    lstart[tid] = hs + woff - hv;
  }
  __syncthreads();
#pragma unroll
  for (int j = 0; j < 16; j++) {
    u32 bin = recs[j] >> 24;
    staged[lstart[bin] + rr[j]] = recs[j];
  }
  if (tid < NCOARSE) {
    u32 c = hist[tid];
    gbase[tid] = c ? atomicAdd(&cursor[(size_t)g * NCOARSE + tid], c) : 0u;
  }
  __syncthreads();
  u64* bn = binned + (size_t)g * NCOARSE * SLOT;
  for (int s = tid; s < CHUNK; s += 512) {
    u32 v = staged[s];
    u32 bin = v >> 24;
    u32 e = v & EMASK17;
    u32 label = (v >> 17) & 3u;
    u32 k1 = tf_bits(sk[0], sk[1], e);
    u32 off = gbase[bin] + ((u32)s - lstart[bin]);
    if (off < SLOT)
      bn[(size_t)bin * SLOT + off] = ((u64)k1 << 19) | ((u64)e << 2) | (u64)label;  // SLOT=704 = mean+8.5 sigma (CHUNK-invariant: per-batch bucket total)
  }
  __syncthreads();
  if (tid < 2) atomicAdd(&meta[(size_t)g * 16 + 2 + tid], cntPN[tid]);
}

// One block = 8 buckets, 256 threads (8 blocks/CU — R15 occupancy lesson).
// 4 barriers/bucket (hist-zero folded into scan; rank uses sstart-diff).
// Counting sub-sort + element-wise exact rank (branch-free u64 compare), k2,
// dynamic-threshold survivor append via LDS staging + 2 atomics/block.
__global__ __launch_bounds__(256) void passB_kernel(const u32* __restrict__ cursor,
                                                    const u64* __restrict__ binned,
                                                    u32* __restrict__ meta,
                                                    u64* __restrict__ posbuf, u64* __restrict__ negbuf,
                                                    int batch0) {
  __shared__ u32 sk2[2];
  __shared__ u32 sth[2];
  __shared__ u64 keys[SLOT];
  __shared__ u32 hist[NSUB];
  __shared__ u32 sstart[NSUB];
  __shared__ u32 wtot[4];
  __shared__ u32 bstart[NCOARSE];
  __shared__ u32 bcnt[NCOARSE];
  __shared__ u64 sposb[SPOSCAP];
  __shared__ u64 snegb[SNEGCAP];
  __shared__ u32 lcb[2], lbase[2];
  int g = blockIdx.y;
  int tid = threadIdx.x;
  if (tid == 0) {
    u32 a, c;
    batch_round_key(batch0 + g, 2, a, c); sk2[0] = a; sk2[1] = c;
    lcb[0] = 0; lcb[1] = 0;
    u32 np = meta[(size_t)g * 16 + 2], nn = meta[(size_t)g * 16 + 3];
    u32 qp = np < 128 ? np : 128;
    u32 qn = 512 - qp;
    u32 needp = qp + 96, needn = qn + 160;
    u32 tp = 0, tn = 0;
    if (np > needp) { u32 d = (256u * needp + np - 1) / np; if (d < 256) tp = 256 - d; }
    if (nn > needn) { u32 d = (256u * needn + nn - 1) / nn; if (d < 256) tn = 256 - d; }
    sth[0] = tp; sth[1] = tn;
  }
  // zero hist once (per-bucket zeroing happens in the scan phase)
  hist[tid] = 0; hist[tid + 256] = 0; hist[tid + 512] = 0; hist[tid + 768] = 0;
  // block-local exclusive scan of the 256 bucket counts (256 threads)
  {
    u32 bv = cursor[(size_t)g * NCOARSE + tid];
    u32 bs = bv;
#pragma unroll
    for (int off = 1; off < 64; off <<= 1) {
      u32 t2 = __shfl_up(bs, off, 64);
      if ((tid & 63) >= off) bs += t2;
    }
    if ((tid & 63) == 63) wtot[tid >> 6] = bs;
    __syncthreads();
    u32 woff = 0;
    for (int w = 0; w < (tid >> 6); w++) woff += wtot[w];
    bstart[tid] = bs + woff - bv;
    bcnt[tid] = bv;
  }
  __syncthreads();
  const u64* bn = binned + (size_t)g * NCOARSE * SLOT;
  u32 tp = sth[0], tn = sth[1];
  for (int q = 0; q < 8; q++) {
    u32 bin = blockIdx.x * 8 + q;
    u32 cb = bcnt[bin];
    if (cb > SLOT) cb = SLOT;
    u32 start = bstart[bin];
    // phase 1: load + sub-bin tickets (hist zeroed by previous iteration)
    u64 mykey[3]; u32 mysr[3];
#pragma unroll
    for (int t = 0; t < 3; t++) {
      int i = tid + t * 256;
      if (i < (int)cb) {
        u64 key = bn[(size_t)bin * SLOT + i];
        u32 sub = (u32)(key >> 33) & 0x3FFu;
        u32 r = atomicAdd(&hist[sub], 1u);
        mykey[t] = key;
        mysr[t] = (sub << 10) | r;
      } else {
        mysr[t] = 0xFFFFFFFFu;
      }
    }
    __syncthreads();
    // phase 2: scan over 1024 sub-bins (thread owns 4t..4t+3) + re-zero hist
    u32 h0 = hist[4 * tid], h1 = hist[4 * tid + 1], h2 = hist[4 * tid + 2], h3 = hist[4 * tid + 3];
    u32 s = h0 + h1 + h2 + h3;
    u32 v = s;
#pragma unroll
    for (int off = 1; off < 64; off <<= 1) {
      u32 t2 = __shfl_up(v, off, 64);
      if ((tid & 63) >= off) v += t2;
    }
    if ((tid & 63) == 63) wtot[tid >> 6] = v;
    hist[4 * tid] = 0; hist[4 * tid + 1] = 0; hist[4 * tid + 2] = 0; hist[4 * tid + 3] = 0;
    __syncthreads();
    u32 woff = 0;
    for (int w = 0; w < (tid >> 6); w++) woff += wtot[w];
    u32 excl = v + woff - s;
    sstart[4 * tid] = excl;
    sstart[4 * tid + 1] = excl + h0;
    sstart[4 * tid + 2] = excl + h0 + h1;
    sstart[4 * tid + 3] = excl + h0 + h1 + h2;
    __syncthreads();
    // phase 3: scatter into sub-bin-grouped order
#pragma unroll
    for (int t = 0; t < 3; t++) {
      if (mysr[t] != 0xFFFFFFFFu)
        keys[sstart[mysr[t] >> 10] + (mysr[t] & 0x3FFu)] = mykey[t];
    }
    __syncthreads();
    // phase 4: element-wise exact rank (h via sstart-diff) + k2 + append
#pragma unroll
    for (int t = 0; t < 3; t++) {
      int i = tid + t * 256;
      if (i < (int)cb) {
        u64 ki = keys[i];
        u32 sub = (u32)(ki >> 33) & 0x3FFu;
        u32 s0 = sstart[sub];
        u32 nxt = (sub == 1023u) ? cb : sstart[sub + 1];
        u32 r = 0;
        for (u32 j = s0; j < nxt; j++) {
          if (keys[j] < ki) r++;  // branch-free exact (e unique in key)
        }
        u32 p1 = start + s0 + r;
        u32 label = (u32)ki & 3u;
        if (label) {
          u32 e = (u32)(ki >> 2) & EMASK17;
          u32 k2 = tf_bits(sk2[0], sk2[1], p1);
          u32 b8 = k2 >> 24;
          u64 rec = ((u64)p1 << 32) | e;
          if (label == 1) {
            if (b8 >= tp) {
              u32 rr2 = atomicAdd(&lcb[0], 1u);
              if (rr2 < SPOSCAP) sposb[rr2] = rec;
              else {
                u32 s2 = atomicAdd(&meta[(size_t)g * 16], 1u);
                if (s2 < POSCAP) posbuf[(size_t)g * POSCAP + s2] = rec;
              }
            }
          } else {
            if (b8 >= tn) {
              u32 rr2 = atomicAdd(&lcb[1], 1u);
              if (rr2 < SNEGCAP) snegb[rr2] = rec;
              else {
                u32 s2 = atomicAdd(&meta[(size_t)g * 16 + 1], 1u);
                if (s2 < NEGCAP) negbuf[(size_t)g * NEGCAP + s2] = rec;
              }
            }
          }
        }
      }
    }
    __syncthreads();
  }
  if (tid < 2) {
    u32 n = lcb[tid]; u32 cap = tid ? SNEGCAP : SPOSCAP; if (n > cap) n = cap;
    lbase[tid] = n ? atomicAdd(&meta[(size_t)g * 16 + tid], n) : 0u;
  }
  __syncthreads();
  {
    u32 n0 = lcb[0]; if (n0 > SPOSCAP) n0 = SPOSCAP;
    for (u32 i = tid; i < n0; i += 256) {
      u32 s2 = lbase[0] + i;
      if (s2 < POSCAP) posbuf[(size_t)g * POSCAP + s2] = sposb[i];
    }
    u32 n1 = lcb[1]; if (n1 > SNEGCAP) n1 = SNEGCAP;
    for (u32 i = tid; i < n1; i += 256) {
      u32 s2 = lbase[1] + i;
      if (s2 < NEGCAP) negbuf[(size_t)g * NEGCAP + s2] = snegb[i];
    }
  }
}

// Per batch: rank survivors by full (k2,p1) desc. 8x-unrolled zero-padded
// broadcast rank loops; pos (threads 0-511) and neg (512-1023) concurrent.
__global__ __launch_bounds__(1024) void select_final_kernel(const u32* __restrict__ meta,
                                                            const u64* __restrict__ posbuf,
                                                            const u64* __restrict__ negbuf,
                                                            int* __restrict__ out, int batch0) {
  int g = blockIdx.x, tid = threadIdx.x, b = batch0 + g;
  __shared__ u32 sk2[2];
  __shared__ u64 keyP[POSCAP + 8];
  __shared__ u32 valP[POSCAP];
  __shared__ u64 keyN[NEGCAP + 8];
  __shared__ u32 valN[NEGCAP];
  __shared__ int sel[512];
  if (tid == 0) { u32 a, c; batch_round_key(b, 2, a, c); sk2[0] = a; sk2[1] = c; }
  u32 np = meta[(size_t)g * 16 + 2];
  u32 qp = np < 128 ? np : 128;
  u32 qn = 512 - qp;
  u32 cp = meta[(size_t)g * 16]; if (cp > POSCAP) cp = POSCAP;
  u32 cn = meta[(size_t)g * 16 + 1]; if (cn > NEGCAP) cn = NEGCAP;
  u32 cp8 = (cp + 7) & ~7u;
  u32 cn8 = (cn + 7) & ~7u;
  if (tid < 512) sel[tid] = 0;
  __syncthreads();

  if (tid < 512) {
    for (u32 i = tid; i < cp8; i += 512) {
      if (i < cp) {
        u64 rec = posbuf[(size_t)g * POSCAP + i];
        u32 p1 = (u32)(rec >> 32);
        keyP[i] = ((u64)tf_bits(sk2[0], sk2[1], p1) << 32) | p1;
        valP[i] = (u32)rec;
      } else {
        keyP[i] = 0ull;
      }
    }
  } else {
    u32 t2 = tid - 512;
    for (u32 i = t2; i < cn8; i += 512) {
      if (i < cn) {
        u64 rec = negbuf[(size_t)g * NEGCAP + i];
        u32 p1 = (u32)(rec >> 32);
        keyN[i] = ((u64)tf_bits(sk2[0], sk2[1], p1) << 32) | p1;
        valN[i] = (u32)rec;
      } else {
        keyN[i] = 0ull;
      }
    }
  }
  __syncthreads();

  if (tid < 512) {
#pragma unroll
    for (int t = 0; t < 3; t++) {
      u32 i = tid + t * 512;
      if (i < cp) {
        u64 mk = keyP[i];
        u32 r = 0;
        for (u32 j = 0; j < cp8; j += 8) {
          r += (keyP[j] > mk) + (keyP[j + 1] > mk) + (keyP[j + 2] > mk) + (keyP[j + 3] > mk) +
               (keyP[j + 4] > mk) + (keyP[j + 5] > mk) + (keyP[j + 6] > mk) + (keyP[j + 7] > mk);
        }
        if (r < qp) sel[r] = (int)valP[i];
      }
    }
  } else {
    u32 t2 = tid - 512;
#pragma unroll
    for (int t = 0; t < 3; t++) {
      u32 i = t2 + t * 512;
      if (i < cn) {
        u64 mk = keyN[i];
        u32 r = 0;
        for (u32 j = 0; j < cn8; j += 8) {
          r += (keyN[j] > mk) + (keyN[j + 1] > mk) + (keyN[j + 2] > mk) + (keyN[j + 3] > mk) +
               (keyN[j + 4] > mk) + (keyN[j + 5] > mk) + (keyN[j + 6] > mk) + (keyN[j + 7] > mk);
        }
        if (r < qn) sel[qp + r] = (int)valN[i];
      }
    }
  }
  __syncthreads();

  if (tid < 512) {
    int v = sel[tid];
    u32 r = 0;
    for (int j = 0; j < 512; j += 8) {
      r += (sel[j] < v) + (sel[j + 1] < v) + (sel[j + 2] < v) + (sel[j + 3] < v) +
           (sel[j + 4] < v) + (sel[j + 5] < v) + (sel[j + 6] < v) + (sel[j + 7] < v);
    }
    out[(size_t)b * 512 + r] = v;
  }
}

extern "C" void kernel_launch(void* const* d_in, const int* in_sizes, int n_in,
                              void* d_out, int out_size, void* d_ws, size_t ws_size,
                              hipStream_t stream) {
  const int* pos = (const int*)d_in[0];
  const int* neg = (const int*)d_in[1];
  const int* ign = (const int*)d_in[2];
  int* out = (int*)d_out;

  // zero region per batch: cursor 1KB + meta 64B
  size_t perBatch = (NCOARSE + 16) * 4 + (size_t)NCOARSE * SLOT * 8 +
                    (size_t)POSCAP * 8 + (size_t)NEGCAP * 8;
  int G = (int)(ws_size / perBatch);
  if (G > BATCH) G = BATCH;
  if (G < 1) G = 1;

  char* p = (char*)d_ws;
  u32* cursor = (u32*)p;            p += (size_t)G * NCOARSE * 4;
  u32* meta = (u32*)p;              p += (size_t)G * 16 * 4;  // 64B stride per batch
  size_t zeroBytes = (size_t)p - (size_t)d_ws;
  u64* binned = (u64*)p;            p += (size_t)G * NCOARSE * SLOT * 8;
  u64* posbuf = (u64*)p;            p += (size_t)G * POSCAP * 8;
  u64* negbuf = (u64*)p;            p += (size_t)G * NEGCAP * 8;

  for (int batch0 = 0; batch0 < BATCH; batch0 += G) {
    int Gi = (BATCH - batch0 < G) ? (BATCH - batch0) : G;
    hipMemsetAsync(d_ws, 0, zeroBytes, stream);
    dim3 gridS(NN / CHUNK, Gi);
    scatterA_kernel<<<gridS, 512, 0, stream>>>(cursor, meta, binned, pos, neg, ign, batch0);
    dim3 gridP(NCOARSE / 8, Gi);
    passB_kernel<<<gridP, 256, 0, stream>>>(cursor, binned, meta, posbuf, negbuf, batch0);
    select_final_kernel<<<Gi, 1024, 0, stream>>>(meta, posbuf, negbuf, out, batch0);
  }
}

// Round 20
// 216.094 us; speedup vs baseline: 1.0247x; 1.0247x over previous
//
#include <hip/hip_runtime.h>
#include <stdint.h>

#define BATCH 64
#define NN 131072
#define NCOARSE 256
#define SLOT 704
#define CHUNK 4096
#define NSUB 1024
#define EMASK17 0x1FFFFu
#define POSCAP 1536
#define NEGCAP 1536
#define SPOSCAP 96
#define SNEGCAP 160

typedef uint32_t u32;
typedef uint64_t u64;

__device__ __forceinline__ u32 rotl32(u32 v, int d) { return (v << d) | (v >> (32 - d)); }

// Exact port of JAX threefry2x32 block cipher
__device__ __forceinline__ void threefry2x32(u32 k0, u32 k1, u32 x0, u32 x1, u32& o0, u32& o1) {
  u32 ks2 = k0 ^ k1 ^ 0x1BD11BDAu;
  x0 += k0; x1 += k1;
#define TF_R(r) { x0 += x1; x1 = rotl32(x1, r); x1 ^= x0; }
  TF_R(13) TF_R(15) TF_R(26) TF_R(6)
  x0 += k1;  x1 += ks2 + 1u;
  TF_R(17) TF_R(29) TF_R(16) TF_R(24)
  x0 += ks2; x1 += k0 + 2u;
  TF_R(13) TF_R(15) TF_R(26) TF_R(6)
  x0 += k0;  x1 += k1 + 3u;
  TF_R(17) TF_R(29) TF_R(16) TF_R(24)
  x0 += k1;  x1 += ks2 + 4u;
  TF_R(13) TF_R(15) TF_R(26) TF_R(6)
  x0 += ks2; x1 += k0 + 5u;
#undef TF_R
  o0 = x0; o1 = x1;
}

// threefry_partitionable: bits[i] = o0 ^ o1 of cipher(key, (0, i))
__device__ __forceinline__ u32 tf_bits(u32 k0, u32 k1, u32 i) {
  u32 o0, o1;
  threefry2x32(k0, k1, 0u, i, o0, o1);
  return o0 ^ o1;
}

// kb = cipher((0,42),(0,b)); round1 sub = cipher(kb,(0,1));
// round2 sub = cipher(cipher(kb,(0,0)),(0,1))
__device__ void batch_round_key(int b, int round, u32& rk0, u32& rk1) {
  u32 kb0, kb1;
  threefry2x32(0u, 42u, 0u, (u32)b, kb0, kb1);
  if (round == 1) { threefry2x32(kb0, kb1, 0u, 1u, rk0, rk1); return; }
  u32 c0, c1;
  threefry2x32(kb0, kb1, 0u, 0u, c0, c1);
  threefry2x32(c0, c1, 0u, 1u, rk0, rk1);
}

// meta[g*16+ .]: 0 = pos survivor count, 1 = neg survivor count, 2 = np, 3 = nn.
// 64B stride per batch (R8 lesson: returning atomics to one line serialize).

// Coarse bucket scatter, 512 threads x 8 elems. binned carries the FULL u64
// key (k1<<19 | e<<2 | label) — R17/R19 lesson: k1 recompute anywhere on a
// dependent path costs more wall time than the write bytes it saves (R17:
// passB phase-1 critical path, +16us; R19: VGPR 28->40, occupancy -13pt).
__global__ __launch_bounds__(512) void scatterA_kernel(u32* __restrict__ cursor, u32* __restrict__ meta,
                                                       u64* __restrict__ binned,
                                                       const int* __restrict__ posg, const int* __restrict__ negg,
                                                       const int* __restrict__ igng, int batch0) {
  __shared__ u32 sk[2];
  __shared__ u32 hist[NCOARSE];
  __shared__ u32 lstart[NCOARSE];
  __shared__ u32 gbase[NCOARSE];
  __shared__ u64 staged[CHUNK];
  __shared__ u32 wtot4[4];
  __shared__ u32 cntPN[2];
  int g = blockIdx.y;
  int b = batch0 + g;
  int tid = threadIdx.x;
  if (tid == 0) { u32 k0, k1; batch_round_key(b, 1, k0, k1); sk[0] = k0; sk[1] = k1; }
  if (tid < 2) cntPN[tid] = 0;
  if (tid < NCOARSE) hist[tid] = 0;
  __syncthreads();
  u32 base = blockIdx.x * CHUNK;
  u64 recs[8]; u32 rr[8];
  u32 myp = 0, myn = 0;
  const int4* P4 = (const int4*)(posg + (size_t)b * NN);
  const int4* Q4 = (const int4*)(negg + (size_t)b * NN);
  const int4* I4 = (const int4*)(igng + (size_t)b * NN);
#pragma unroll
  for (int j = 0; j < 2; j++) {
    u32 e0 = base + j * 2048 + tid * 4;
    int4 pv = P4[e0 >> 2];
    int4 nv = Q4[e0 >> 2];
    int4 iv = I4[e0 >> 2];
#pragma unroll
    for (int m = 0; m < 4; m++) {
      u32 e = e0 + m;
      int p = (&pv.x)[m] != 0, n = (&nv.x)[m] != 0, ig = (&iv.x)[m] != 0;
      u32 label = ((p | n) && !ig) ? (p ? 1u : 2u) : 0u;
      myp += (label == 1);
      myn += (label == 2);
      u32 k1 = tf_bits(sk[0], sk[1], e);
      u32 bin = k1 >> 24;
      rr[j * 4 + m] = atomicAdd(&hist[bin], 1u);
      recs[j * 4 + m] = ((u64)k1 << 19) | ((u64)e << 2) | (u64)label;
    }
  }
#pragma unroll
  for (int off = 32; off > 0; off >>= 1) {
    myp += __shfl_down(myp, off, 64);
    myn += __shfl_down(myn, off, 64);
  }
  if ((tid & 63) == 0) { atomicAdd(&cntPN[0], myp); atomicAdd(&cntPN[1], myn); }
  __syncthreads();
  // shfl-based exclusive scan of hist (256 entries, first 256 threads)
  u32 hv = 0, hs = 0;
  if (tid < NCOARSE) {
    hv = hist[tid];
    hs = hv;
#pragma unroll
    for (int off = 1; off < 64; off <<= 1) {
      u32 t = __shfl_up(hs, off, 64);
      if ((tid & 63) >= off) hs += t;
    }
    if ((tid & 63) == 63) wtot4[tid >> 6] = hs;
  }
  __syncthreads();
  if (tid < NCOARSE) {
    u32 woff = 0;
    for (int w = 0; w < (tid >> 6); w++) woff += wtot4[w];
    lstart[tid] = hs + woff - hv;
  }
  __syncthreads();
#pragma unroll
  for (int j = 0; j < 8; j++) {
    u32 bin = (u32)(recs[j] >> 43);
    staged[lstart[bin] + rr[j]] = recs[j];
  }
  if (tid < NCOARSE) {
    u32 c = hist[tid];
    gbase[tid] = c ? atomicAdd(&cursor[(size_t)g * NCOARSE + tid], c) : 0u;
  }
  __syncthreads();
  u64* bn = binned + (size_t)g * NCOARSE * SLOT;
  for (int s = tid; s < CHUNK; s += 512) {
    u64 v = staged[s];
    u32 bin = (u32)(v >> 43);
    u32 off = gbase[bin] + ((u32)s - lstart[bin]);
    if (off < SLOT) bn[(size_t)bin * SLOT + off] = v;  // SLOT=704 = mean+8.5 sigma
  }
  __syncthreads();
  if (tid < 2) atomicAdd(&meta[(size_t)g * 16 + 2 + tid], cntPN[tid]);
}

// One block = 8 buckets, 256 threads (8 blocks/CU — R15 occupancy lesson).
// 4 barriers/bucket (hist-zero folded into scan; rank uses sstart-diff).
// Counting sub-sort + element-wise exact rank (branch-free u64 compare), k2,
// dynamic-threshold survivor append via LDS staging + 2 atomics/block.
__global__ __launch_bounds__(256) void passB_kernel(const u32* __restrict__ cursor,
                                                    const u64* __restrict__ binned,
                                                    u32* __restrict__ meta,
                                                    u64* __restrict__ posbuf, u64* __restrict__ negbuf,
                                                    int batch0) {
  __shared__ u32 sk2[2];
  __shared__ u32 sth[2];
  __shared__ u64 keys[SLOT];
  __shared__ u32 hist[NSUB];
  __shared__ u32 sstart[NSUB];
  __shared__ u32 wtot[4];
  __shared__ u32 bstart[NCOARSE];
  __shared__ u32 bcnt[NCOARSE];
  __shared__ u64 sposb[SPOSCAP];
  __shared__ u64 snegb[SNEGCAP];
  __shared__ u32 lcb[2], lbase[2];
  int g = blockIdx.y;
  int tid = threadIdx.x;
  if (tid == 0) {
    u32 a, c;
    batch_round_key(batch0 + g, 2, a, c); sk2[0] = a; sk2[1] = c;
    lcb[0] = 0; lcb[1] = 0;
    u32 np = meta[(size_t)g * 16 + 2], nn = meta[(size_t)g * 16 + 3];
    u32 qp = np < 128 ? np : 128;
    u32 qn = 512 - qp;
    u32 needp = qp + 96, needn = qn + 160;
    u32 tp = 0, tn = 0;
    if (np > needp) { u32 d = (256u * needp + np - 1) / np; if (d < 256) tp = 256 - d; }
    if (nn > needn) { u32 d = (256u * needn + nn - 1) / nn; if (d < 256) tn = 256 - d; }
    sth[0] = tp; sth[1] = tn;
  }
  // zero hist once (per-bucket zeroing happens in the scan phase)
  hist[tid] = 0; hist[tid + 256] = 0; hist[tid + 512] = 0; hist[tid + 768] = 0;
  // block-local exclusive scan of the 256 bucket counts (256 threads)
  {
    u32 bv = cursor[(size_t)g * NCOARSE + tid];
    u32 bs = bv;
#pragma unroll
    for (int off = 1; off < 64; off <<= 1) {
      u32 t2 = __shfl_up(bs, off, 64);
      if ((tid & 63) >= off) bs += t2;
    }
    if ((tid & 63) == 63) wtot[tid >> 6] = bs;
    __syncthreads();
    u32 woff = 0;
    for (int w = 0; w < (tid >> 6); w++) woff += wtot[w];
    bstart[tid] = bs + woff - bv;
    bcnt[tid] = bv;
  }
  __syncthreads();
  const u64* bn = binned + (size_t)g * NCOARSE * SLOT;
  u32 tp = sth[0], tn = sth[1];
  for (int q = 0; q < 8; q++) {
    u32 bin = blockIdx.x * 8 + q;
    u32 cb = bcnt[bin];
    if (cb > SLOT) cb = SLOT;
    u32 start = bstart[bin];
    // phase 1: load + sub-bin tickets (hist zeroed by previous iteration)
    u64 mykey[3]; u32 mysr[3];
#pragma unroll
    for (int t = 0; t < 3; t++) {
      int i = tid + t * 256;
      if (i < (int)cb) {
        u64 key = bn[(size_t)bin * SLOT + i];
        u32 sub = (u32)(key >> 33) & 0x3FFu;
        u32 r = atomicAdd(&hist[sub], 1u);
        mykey[t] = key;
        mysr[t] = (sub << 10) | r;
      } else {
        mysr[t] = 0xFFFFFFFFu;
      }
    }
    __syncthreads();
    // phase 2: scan over 1024 sub-bins (thread owns 4t..4t+3) + re-zero hist
    u32 h0 = hist[4 * tid], h1 = hist[4 * tid + 1], h2 = hist[4 * tid + 2], h3 = hist[4 * tid + 3];
    u32 s = h0 + h1 + h2 + h3;
    u32 v = s;
#pragma unroll
    for (int off = 1; off < 64; off <<= 1) {
      u32 t2 = __shfl_up(v, off, 64);
      if ((tid & 63) >= off) v += t2;
    }
    if ((tid & 63) == 63) wtot[tid >> 6] = v;
    hist[4 * tid] = 0; hist[4 * tid + 1] = 0; hist[4 * tid + 2] = 0; hist[4 * tid + 3] = 0;
    __syncthreads();
    u32 woff = 0;
    for (int w = 0; w < (tid >> 6); w++) woff += wtot[w];
    u32 excl = v + woff - s;
    sstart[4 * tid] = excl;
    sstart[4 * tid + 1] = excl + h0;
    sstart[4 * tid + 2] = excl + h0 + h1;
    sstart[4 * tid + 3] = excl + h0 + h1 + h2;
    __syncthreads();
    // phase 3: scatter into sub-bin-grouped order
#pragma unroll
    for (int t = 0; t < 3; t++) {
      if (mysr[t] != 0xFFFFFFFFu)
        keys[sstart[mysr[t] >> 10] + (mysr[t] & 0x3FFu)] = mykey[t];
    }
    __syncthreads();
    // phase 4: element-wise exact rank (h via sstart-diff) + k2 + append
#pragma unroll
    for (int t = 0; t < 3; t++) {
      int i = tid + t * 256;
      if (i < (int)cb) {
        u64 ki = keys[i];
        u32 sub = (u32)(ki >> 33) & 0x3FFu;
        u32 s0 = sstart[sub];
        u32 nxt = (sub == 1023u) ? cb : sstart[sub + 1];
        u32 r = 0;
        for (u32 j = s0; j < nxt; j++) {
          if (keys[j] < ki) r++;  // branch-free exact (e unique in key)
        }
        u32 p1 = start + s0 + r;
        u32 label = (u32)ki & 3u;
        if (label) {
          u32 e = (u32)(ki >> 2) & EMASK17;
          u32 k2 = tf_bits(sk2[0], sk2[1], p1);
          u32 b8 = k2 >> 24;
          u64 rec = ((u64)p1 << 32) | e;
          if (label == 1) {
            if (b8 >= tp) {
              u32 rr2 = atomicAdd(&lcb[0], 1u);
              if (rr2 < SPOSCAP) sposb[rr2] = rec;
              else {
                u32 s2 = atomicAdd(&meta[(size_t)g * 16], 1u);
                if (s2 < POSCAP) posbuf[(size_t)g * POSCAP + s2] = rec;
              }
            }
          } else {
            if (b8 >= tn) {
              u32 rr2 = atomicAdd(&lcb[1], 1u);
              if (rr2 < SNEGCAP) snegb[rr2] = rec;
              else {
                u32 s2 = atomicAdd(&meta[(size_t)g * 16 + 1], 1u);
                if (s2 < NEGCAP) negbuf[(size_t)g * NEGCAP + s2] = rec;
              }
            }
          }
        }
      }
    }
    __syncthreads();
  }
  if (tid < 2) {
    u32 n = lcb[tid]; u32 cap = tid ? SNEGCAP : SPOSCAP; if (n > cap) n = cap;
    lbase[tid] = n ? atomicAdd(&meta[(size_t)g * 16 + tid], n) : 0u;
  }
  __syncthreads();
  {
    u32 n0 = lcb[0]; if (n0 > SPOSCAP) n0 = SPOSCAP;
    for (u32 i = tid; i < n0; i += 256) {
      u32 s2 = lbase[0] + i;
      if (s2 < POSCAP) posbuf[(size_t)g * POSCAP + s2] = sposb[i];
    }
    u32 n1 = lcb[1]; if (n1 > SNEGCAP) n1 = SNEGCAP;
    for (u32 i = tid; i < n1; i += 256) {
      u32 s2 = lbase[1] + i;
      if (s2 < NEGCAP) negbuf[(size_t)g * NEGCAP + s2] = snegb[i];
    }
  }
}

// Per batch: rank survivors by full (k2,p1) desc. 8x-unrolled zero-padded
// broadcast rank loops; pos (threads 0-511) and neg (512-1023) concurrent.
__global__ __launch_bounds__(1024) void select_final_kernel(const u32* __restrict__ meta,
                                                            const u64* __restrict__ posbuf,
                                                            const u64* __restrict__ negbuf,
                                                            int* __restrict__ out, int batch0) {
  int g = blockIdx.x, tid = threadIdx.x, b = batch0 + g;
  __shared__ u32 sk2[2];
  __shared__ u64 keyP[POSCAP + 8];
  __shared__ u32 valP[POSCAP];
  __shared__ u64 keyN[NEGCAP + 8];
  __shared__ u32 valN[NEGCAP];
  __shared__ int sel[512];
  if (tid == 0) { u32 a, c; batch_round_key(b, 2, a, c); sk2[0] = a; sk2[1] = c; }
  u32 np = meta[(size_t)g * 16 + 2];
  u32 qp = np < 128 ? np : 128;
  u32 qn = 512 - qp;
  u32 cp = meta[(size_t)g * 16]; if (cp > POSCAP) cp = POSCAP;
  u32 cn = meta[(size_t)g * 16 + 1]; if (cn > NEGCAP) cn = NEGCAP;
  u32 cp8 = (cp + 7) & ~7u;
  u32 cn8 = (cn + 7) & ~7u;
  if (tid < 512) sel[tid] = 0;
  __syncthreads();

  if (tid < 512) {
    for (u32 i = tid; i < cp8; i += 512) {
      if (i < cp) {
        u64 rec = posbuf[(size_t)g * POSCAP + i];
        u32 p1 = (u32)(rec >> 32);
        keyP[i] = ((u64)tf_bits(sk2[0], sk2[1], p1) << 32) | p1;
        valP[i] = (u32)rec;
      } else {
        keyP[i] = 0ull;
      }
    }
  } else {
    u32 t2 = tid - 512;
    for (u32 i = t2; i < cn8; i += 512) {
      if (i < cn) {
        u64 rec = negbuf[(size_t)g * NEGCAP + i];
        u32 p1 = (u32)(rec >> 32);
        keyN[i] = ((u64)tf_bits(sk2[0], sk2[1], p1) << 32) | p1;
        valN[i] = (u32)rec;
      } else {
        keyN[i] = 0ull;
      }
    }
  }
  __syncthreads();

  if (tid < 512) {
#pragma unroll
    for (int t = 0; t < 3; t++) {
      u32 i = tid + t * 512;
      if (i < cp) {
        u64 mk = keyP[i];
        u32 r = 0;
        for (u32 j = 0; j < cp8; j += 8) {
          r += (keyP[j] > mk) + (keyP[j + 1] > mk) + (keyP[j + 2] > mk) + (keyP[j + 3] > mk) +
               (keyP[j + 4] > mk) + (keyP[j + 5] > mk) + (keyP[j + 6] > mk) + (keyP[j + 7] > mk);
        }
        if (r < qp) sel[r] = (int)valP[i];
      }
    }
  } else {
    u32 t2 = tid - 512;
#pragma unroll
    for (int t = 0; t < 3; t++) {
      u32 i = t2 + t * 512;
      if (i < cn) {
        u64 mk = keyN[i];
        u32 r = 0;
        for (u32 j = 0; j < cn8; j += 8) {
          r += (keyN[j] > mk) + (keyN[j + 1] > mk) + (keyN[j + 2] > mk) + (keyN[j + 3] > mk) +
               (keyN[j + 4] > mk) + (keyN[j + 5] > mk) + (keyN[j + 6] > mk) + (keyN[j + 7] > mk);
        }
        if (r < qn) sel[qp + r] = (int)valN[i];
      }
    }
  }
  __syncthreads();

  if (tid < 512) {
    int v = sel[tid];
    u32 r = 0;
    for (int j = 0; j < 512; j += 8) {
      r += (sel[j] < v) + (sel[j + 1] < v) + (sel[j + 2] < v) + (sel[j + 3] < v) +
           (sel[j + 4] < v) + (sel[j + 5] < v) + (sel[j + 6] < v) + (sel[j + 7] < v);
    }
    out[(size_t)b * 512 + r] = v;
  }
}

extern "C" void kernel_launch(void* const* d_in, const int* in_sizes, int n_in,
                              void* d_out, int out_size, void* d_ws, size_t ws_size,
                              hipStream_t stream) {
  const int* pos = (const int*)d_in[0];
  const int* neg = (const int*)d_in[1];
  const int* ign = (const int*)d_in[2];
  int* out = (int*)d_out;

  // zero region per batch: cursor 1KB + meta 64B
  size_t perBatch = (NCOARSE + 16) * 4 + (size_t)NCOARSE * SLOT * 8 +
                    (size_t)POSCAP * 8 + (size_t)NEGCAP * 8;
  int G = (int)(ws_size / perBatch);
  if (G > BATCH) G = BATCH;
  if (G < 1) G = 1;

  char* p = (char*)d_ws;
  u32* cursor = (u32*)p;            p += (size_t)G * NCOARSE * 4;
  u32* meta = (u32*)p;              p += (size_t)G * 16 * 4;  // 64B stride per batch
  size_t zeroBytes = (size_t)p - (size_t)d_ws;
  u64* binned = (u64*)p;            p += (size_t)G * NCOARSE * SLOT * 8;
  u64* posbuf = (u64*)p;            p += (size_t)G * POSCAP * 8;
  u64* negbuf = (u64*)p;            p += (size_t)G * NEGCAP * 8;

  for (int batch0 = 0; batch0 < BATCH; batch0 += G) {
    int Gi = (BATCH - batch0 < G) ? (BATCH - batch0) : G;
    hipMemsetAsync(d_ws, 0, zeroBytes, stream);
    dim3 gridS(NN / CHUNK, Gi);
    scatterA_kernel<<<gridS, 512, 0, stream>>>(cursor, meta, binned, pos, neg, ign, batch0);
    dim3 gridP(NCOARSE / 8, Gi);
    passB_kernel<<<gridP, 256, 0, stream>>>(cursor, binned, meta, posbuf, negbuf, batch0);
    select_final_kernel<<<Gi, 1024, 0, stream>>>(meta, posbuf, negbuf, out, batch0);
  }
}